// Round 14
// baseline (107.228 us; speedup 1.0000x reference)
//
#include <hip/hip_runtime.h>

typedef float f32x4 __attribute__((ext_vector_type(4)));
typedef float f32x16 __attribute__((ext_vector_type(16)));
typedef __bf16 bf16x8 __attribute__((ext_vector_type(8)));
typedef unsigned short u16;
typedef unsigned int u32;
typedef u16 u16x8 __attribute__((ext_vector_type(8)));
typedef u16 u16x4 __attribute__((ext_vector_type(4)));
typedef u32 u32x4 __attribute__((ext_vector_type(4)));

#define SCALE2F (0.044194173824159216f * 1.4426950408889634f)   // 1/sqrt(512) * log2(e)
#define UNSCALE (1.0f / SCALE2F)

__device__ __forceinline__ u16 f2bf(float x){ return __builtin_bit_cast(u16, (__bf16)x); }
__device__ __forceinline__ float bf2f(u16 h){ unsigned u = ((unsigned)h) << 16; return __builtin_bit_cast(float, u); }
// XOR swizzle within a 128B row: involution, bijective per 128B wrap
__device__ __forceinline__ int swz(int r, int byteInRow){ return (r*128 + byteInRow) ^ ((r & 7) << 4); }
// async global->LDS, 16B per lane; LDS dest must be wave-uniform base + lane*16
__device__ __forceinline__ void gload16(const void* g, void* l) {
  __builtin_amdgcn_global_load_lds(
      (const __attribute__((address_space(1))) void*)g,
      (__attribute__((address_space(3))) void*)l, 16, 0, 0);
}
__device__ __forceinline__ u32 cvtpk(float lo, float hi_) {
  u32 r;
  asm("v_cvt_pk_bf16_f32 %0, %1, %2" : "=v"(r) : "v"(lo), "v"(hi_));
  return r;
}
// v_permlane32_swap_b32: a' = {a.lo32, b.lo32}, b' = {a.hi32, b.hi32}
__device__ __forceinline__ void swap32(u32 &a, u32 &b) {
  asm("v_permlane32_swap_b32 %0, %1" : "+v"(a), "+v"(b));
}

#define MFMA(a,b,c)   __builtin_amdgcn_mfma_f32_16x16x32_bf16((a),(b),(c),0,0,0)
#define MFMA32(a,b,c) __builtin_amdgcn_mfma_f32_32x32x16_bf16((a),(b),(c),0,0,0)

// ---------------- weight prep: Wt[n][k] = bf16(W[k][n] * sc), 512x512 x4 ----------------
__global__ __launch_bounds__(256) void wprep_k(
    const float* __restrict__ W0, const float* __restrict__ W1,
    const float* __restrict__ W2, const float* __restrict__ W3,
    u16* __restrict__ wt)
{
  __shared__ float tile[64][68];
  const float* Ws[4] = {W0, W1, W2, W3};
  const float* W = Ws[blockIdx.z];
  const float sc = (blockIdx.z == 0) ? SCALE2F : 1.0f;   // fold softmax scale into Wq
  u16* out = wt + (size_t)blockIdx.z * 512 * 512;
  int k0 = blockIdx.x * 64, n0 = blockIdx.y * 64;
  int t = threadIdx.x;
  #pragma unroll
  for (int i = 0; i < 2; ++i) {
    int c = t + i*256; int r = c >> 3, k8 = c & 7;
    const float* src = W + (size_t)(k0 + r)*512 + n0 + k8*8;
    *(f32x4*)&tile[r][k8*8]     = *(const f32x4*)src;
    *(f32x4*)&tile[r][k8*8 + 4] = *(const f32x4*)(src + 4);
  }
  __syncthreads();
  #pragma unroll
  for (int i = 0; i < 2; ++i) {
    int c = t + i*256; int r = c >> 3, k8 = c & 7;
    u16x8 h;
    #pragma unroll
    for (int j = 0; j < 8; ++j) h[j] = f2bf(tile[k8*8 + j][r] * sc);
    *(u16x8*)(out + (size_t)(n0 + r)*512 + k0 + k8*8) = h;
  }
}

// ---------------- projections: uniform 128x128 tiles, 1D grid (gemm, tm, tn) ------------
// gemm 0: Q @ Wq -> qbuf; 1: K @ Wk -> kbuf; 2: K @ Wv -> vt (pre-transposed).
// 8 waves (2x4), 64x32 out each; A fp32 reg-staged -> bf16 LDS; B via gload_lds.
__global__ __launch_bounds__(512) void proj_k(
    const float* __restrict__ Qin, const float* __restrict__ Kin,
    const u16* __restrict__ wt,
    const float* __restrict__ bq, const float* __restrict__ bk, const float* __restrict__ bv,
    u16* __restrict__ qbuf, u16* __restrict__ kbuf, u16* __restrict__ vt)
{
  __shared__ __align__(16) u16 lA[2][128*64];   // 16KB each
  __shared__ __align__(16) u16 lB[2][128*64];   // 16KB each
  int gid = blockIdx.x;
  int gemm = gid >> 8;                // 0..2
  int rem = gid & 255;
  int row0 = (rem >> 2) * 128;        // 64 row-tiles
  int col0 = (rem & 3) * 128;         // 4 col-panels
  const float* A    = (gemm == 0) ? Qin : Kin;
  const u16*   Bt   = wt + (size_t)gemm * 262144;
  const float* bias = (gemm == 0) ? bq : (gemm == 1) ? bk : bv;
  const float bscale = (gemm == 0) ? SCALE2F : 1.0f;

  int t = threadIdx.x, lane = t & 63, wid = t >> 6;
  int wr = wid >> 2, wc = wid & 3;    // 2x4 waves, 64x32 out each
  int l15 = lane & 15, lg = lane >> 4;
  // A staging: thread -> (row 0..127, 16-elem quarter)
  int at = t >> 2, aq = t & 3;
  // B staging: 2 gload rounds of 64 rows; inverse-swizzled source col
  int br = t >> 3;
  int bsrc = ((t & 7) ^ (br & 7)) << 3;
  const float* Arow = A + (size_t)row0 * 512;
  const u16*   Brow = Bt + (size_t)col0 * 512;

  f32x4 acc[4][2] = {};

  auto stageA = [&](int buf, int k0) {
    const float* src = Arow + (size_t)at*512 + k0 + aq*16;
    f32x4 x0 = *(const f32x4*)src;
    f32x4 x1 = *(const f32x4*)(src + 4);
    f32x4 x2 = *(const f32x4*)(src + 8);
    f32x4 x3 = *(const f32x4*)(src + 12);
    u16x8 h0, h1;
    #pragma unroll
    for (int j = 0; j < 4; ++j) {
      h0[j] = f2bf(x0[j]); h0[j+4] = f2bf(x1[j]);
      h1[j] = f2bf(x2[j]); h1[j+4] = f2bf(x3[j]);
    }
    *(u16x8*)((char*)lA[buf] + swz(at, aq*32))      = h0;
    *(u16x8*)((char*)lA[buf] + swz(at, aq*32 + 16)) = h1;
  };

  // prologue
  #pragma unroll
  for (int i = 0; i < 2; ++i)
    gload16(Brow + (size_t)(br + i*64)*512 + bsrc, (char*)lB[0] + i*8192 + t*16);
  stageA(0, 0);
  __syncthreads();

  int cur = 0;
  for (int k0 = 0; k0 < 512; k0 += 64) {
    if (k0 + 64 < 512) {
      #pragma unroll
      for (int i = 0; i < 2; ++i)
        gload16(Brow + (size_t)(br + i*64)*512 + k0 + 64 + bsrc, (char*)lB[cur^1] + i*8192 + t*16);
      stageA(cur^1, k0 + 64);
    }
    const char* lAc = (const char*)lA[cur];
    const char* lBc = (const char*)lB[cur];
    #pragma unroll
    for (int ks = 0; ks < 2; ++ks) {
      bf16x8 af[4], bf[2];
      #pragma unroll
      for (int m = 0; m < 4; ++m)
        af[m] = *(const bf16x8*)(lAc + swz(wr*64 + m*16 + l15, ks*64 + lg*16));
      #pragma unroll
      for (int n = 0; n < 2; ++n)
        bf[n] = *(const bf16x8*)(lBc + swz(wc*32 + n*16 + l15, ks*64 + lg*16));
      #pragma unroll
      for (int m = 0; m < 4; ++m)
        #pragma unroll
        for (int n = 0; n < 2; ++n)
          acc[m][n] = MFMA(af[m], bf[n], acc[m][n]);
    }
    __syncthreads();
    cur ^= 1;
  }

  if (gemm < 2) {
    u16* out = gemm ? kbuf : qbuf;
    #pragma unroll
    for (int m = 0; m < 4; ++m) {
      int rowg = row0 + wr*64 + m*16 + lg*4;
      #pragma unroll
      for (int n = 0; n < 2; ++n) {
        int colg = col0 + wc*32 + n*16 + l15;
        float bvv = bias[colg] * bscale;
        #pragma unroll
        for (int r = 0; r < 4; ++r)
          out[(size_t)(rowg + r)*512 + colg] = f2bf(acc[m][n][r] + bvv);
      }
    }
  } else {   // V: write transposed vt[b][dh][tok]
    #pragma unroll
    for (int m = 0; m < 4; ++m) {
      int rowg = row0 + wr*64 + m*16 + lg*4;
      int b = rowg >> 11, ntok = rowg & 2047;
      #pragma unroll
      for (int n = 0; n < 2; ++n) {
        int colg = col0 + wc*32 + n*16 + l15;
        float bvv = bias[colg];
        u16x4 hv;
        #pragma unroll
        for (int r = 0; r < 4; ++r) hv[r] = f2bf(acc[m][n][r] + bvv);
        *(u16x4*)(vt + ((size_t)b*512 + colg)*2048 + ntok) = hv;
      }
    }
  }
}

// ---------------- flash attention: 8 waves = 4 q-waves x 2 KV-halves, in-block combine --
// 1D grid with XCD-aware decode: all 16 q-blocks of a (b,h) land on the same XCD slots
// (j%8 = bh%8 under round-robin dispatch) so the K/V slice is fetched ~once per XCD.
__device__ __forceinline__ void mk_pb(const f32x16& s, float& ps, bf16x8& f0, bf16x8& f1) {
  float p[16];
  #pragma unroll
  for (int r = 0; r < 16; ++r) p[r] = __builtin_amdgcn_exp2f(s[r]);
  float t0 = (p[0] + p[1])  + (p[2] + p[3]);
  float t1 = (p[4] + p[5])  + (p[6] + p[7]);
  float t2 = (p[8] + p[9])  + (p[10] + p[11]);
  float t3 = (p[12] + p[13]) + (p[14] + p[15]);
  ps += (t0 + t1) + (t2 + t3);
  u32 a0 = cvtpk(p[0],  p[1]),  b0 = cvtpk(p[4],  p[5]);
  u32 a1 = cvtpk(p[2],  p[3]),  b1 = cvtpk(p[6],  p[7]);
  swap32(a0, b0); swap32(a1, b1);
  u32 a2 = cvtpk(p[8],  p[9]),  b2 = cvtpk(p[12], p[13]);
  u32 a3 = cvtpk(p[10], p[11]), b3 = cvtpk(p[14], p[15]);
  swap32(a2, b2); swap32(a3, b3);
  u32x4 w0 = {a0, a1, b0, b1};
  u32x4 w1 = {a2, a3, b2, b3};
  f0 = __builtin_bit_cast(bf16x8, w0);
  f1 = __builtin_bit_cast(bf16x8, w1);
}

__global__ __launch_bounds__(512, 4) void attn_k(
    const u16* __restrict__ qb, const u16* __restrict__ kb,
    const u16* __restrict__ vt, u16* __restrict__ ob)
{
  __shared__ __align__(16) char smem[65536];   // lK: 4x8KB | lV: 4x8KB; combine reuses lK

  int t = threadIdx.x, lane = t & 63, wid = t >> 6;
  // XCD-aware decode of 1D block id (bijective over 512)
  int j = blockIdx.x;
  int xcd = j & 7, slot = j >> 3;
  int qx = slot & 15;
  int bh = ((slot >> 4) << 3) | xcd;
  int b = bh >> 3, h = bh & 7;
  int half = wid >> 2;                         // KV half (0: 0-1023, 1: 1024-2047)
  int qw = wid & 3;
  int q0 = qx * 128 + qw * 32;                 // 4 q-waves x 32 rows
  int l31 = lane & 31, hi = lane >> 5;

  const u16* kbase = kb + ((size_t)b*2048)*512 + h*64;
  const u16* vbase = vt + ((size_t)b*512 + h*64)*2048;

  int sr = t >> 3;                                   // 0..63
  int ssrc = ((t & 7) ^ (sr & 7)) << 3;              // inverse-swizzled src col (elements)

#define LKB(hf, bf) (smem + ((hf)*2 + (bf))*8192)
#define LVB(hf, bf) (smem + 32768 + ((hf)*2 + (bf))*8192)
#define STAGE(buf, off)                                                           \
  gload16(kbase + (size_t)((off) + sr)*512 + ssrc,        LKB(0,buf) + t*16);     \
  gload16(kbase + (size_t)((off) + 1024 + sr)*512 + ssrc, LKB(1,buf) + t*16);     \
  gload16(vbase + (size_t)sr*2048 + (off) + ssrc,         LVB(0,buf) + t*16);     \
  gload16(vbase + (size_t)sr*2048 + (off) + 1024 + ssrc,  LVB(1,buf) + t*16);

  bf16x8 aq[4];
  {
    const u16* qp = qb + ((size_t)(b*2048 + q0 + l31))*512 + h*64 + hi*8;
    #pragma unroll
    for (int ks = 0; ks < 4; ++ks) aq[ks] = *(const bf16x8*)(qp + ks*16);
  }

  f32x16 acc[2] = {};
  float ps = 0.0f;

  STAGE(0, 0);
  __syncthreads();

  int cur = 0;
  for (int i = 0; i < 16; ++i) {
    if (i + 1 < 16) { STAGE(cur^1, (i+1)*64); }
    const char* lKc = LKB(half, cur);
    const char* lVc = LVB(half, cur);
    bf16x8 pb[4];
    #pragma unroll
    for (int n = 0; n < 2; ++n) {
      f32x16 s = {};
      #pragma unroll
      for (int ks = 0; ks < 4; ++ks) {
        bf16x8 kf = *(const bf16x8*)(lKc + swz(n*32 + l31, ks*32 + hi*16));
        s = MFMA32(kf, aq[ks], s);
      }
      mk_pb(s, ps, pb[2*n], pb[2*n+1]);
    }
    #pragma unroll
    for (int m = 0; m < 2; ++m)
      #pragma unroll
      for (int ks = 0; ks < 4; ++ks) {
        bf16x8 vf = *(const bf16x8*)(lVc + swz(m*32 + l31, ks*32 + hi*16));
        acc[m] = MFMA32(vf, pb[ks], acc[m]);
      }
    __syncthreads();
    cur ^= 1;
  }
#undef STAGE

  // ---- in-block combine: half-1 -> LDS (pitch 68 f32, region 2208 f32 per q-wave) ----
  ps += __shfl_xor(ps, 32, 64);
  float* cb = (float*)smem;
  if (half == 1) {
    float* dst = cb + qw * 2208;
    #pragma unroll
    for (int m = 0; m < 2; ++m)
      #pragma unroll
      for (int rq = 0; rq < 4; ++rq) {
        f32x4 v = {acc[m][rq*4], acc[m][rq*4+1], acc[m][rq*4+2], acc[m][rq*4+3]};
        *(f32x4*)(dst + l31*68 + m*32 + rq*8 + hi*4) = v;
      }
    if (hi == 0) dst[2176 + l31] = ps;
  }
  __syncthreads();
  if (half == 0) {
    const float* src = cb + qw * 2208;
    float inv = 1.0f / (ps + src[2176 + l31]);
    u16* obase = ob + ((size_t)(b*2048 + q0 + l31))*512 + h*64;
    const u16* qrb = qb + ((size_t)(b*2048 + q0 + l31))*512 + h*64;
    #pragma unroll
    for (int m = 0; m < 2; ++m)
      #pragma unroll
      for (int rq = 0; rq < 4; ++rq) {
        f32x4 other = *(const f32x4*)(src + l31*68 + m*32 + rq*8 + hi*4);
        u16x4 qr4 = *(const u16x4*)(qrb + m*32 + rq*8 + hi*4);
        u16x4 o4;
        #pragma unroll
        for (int e = 0; e < 4; ++e)
          o4[e] = f2bf((acc[m][rq*4 + e] + other[e])*inv + bf2f(qr4[e])*UNSCALE);
        *(u16x4*)(obase + m*32 + rq*8 + hi*4) = o4;
      }
  }
}

// ---------------- fused tail: LN0 (on-the-fly) -> Wo GEMM + ReLU + residual -> LN1 ------
__global__ __launch_bounds__(512) void tail_k(
    const u16* __restrict__ ob, const u16* __restrict__ Bt,
    const float* __restrict__ bo,
    const float* __restrict__ g0, const float* __restrict__ b0,
    const float* __restrict__ g1, const float* __restrict__ b1,
    float* __restrict__ out)
{
  __shared__ __align__(16) u16 lA[2][32*64];     // 4KB each
  __shared__ __align__(16) u16 lB[2][512*64];    // 64KB each
  __shared__ float mu0[32], rs0[32], mu1[32], rs1[32];
  __shared__ float ps1[32][8], ss1[32][8];

  int row0 = blockIdx.x * 32;
  int t = threadIdx.x, lane = t & 63, wid = t >> 6;
  int l15 = lane & 15, lg = lane >> 4;

  // ---- LN0 stats: 16 threads per row, 32 elems each ----
  {
    int r = t >> 4, c0 = (t & 15) * 32;
    const u16* xp = ob + (size_t)(row0 + r)*512 + c0;
    float s = 0.0f, ss = 0.0f;
    #pragma unroll
    for (int j = 0; j < 4; ++j) {
      u16x8 v = *(const u16x8*)(xp + j*8);
      #pragma unroll
      for (int e = 0; e < 8; ++e) { float f = bf2f(v[e]); s += f; ss += f*f; }
    }
    #pragma unroll
    for (int m = 1; m < 16; m <<= 1) { s += __shfl_xor(s, m, 64); ss += __shfl_xor(ss, m, 64); }
    if ((t & 15) == 0) {
      float mu = s * (1.0f/512.0f);
      float var = ss * (1.0f/512.0f) - mu*mu;
      mu0[r] = mu; rs0[r] = rsqrtf(var + 1e-5f);
    }
  }
  __syncthreads();

  int ar = t >> 3, ak8 = t & 7;
  int br = t >> 3;
  int bsrc = ((t & 7) ^ (br & 7)) << 3;

  auto stageA = [&](int buf, int k0) {
    if (t < 256) {
      u16x8 x = *(const u16x8*)(ob + (size_t)(row0 + ar)*512 + k0 + ak8*8);
      f32x4 gv0 = *(const f32x4*)(g0 + k0 + ak8*8);
      f32x4 gv1 = *(const f32x4*)(g0 + k0 + ak8*8 + 4);
      f32x4 bv0 = *(const f32x4*)(b0 + k0 + ak8*8);
      f32x4 bv1 = *(const f32x4*)(b0 + k0 + ak8*8 + 4);
      float mu = mu0[ar], rs = rs0[ar];
      u16x8 h;
      #pragma unroll
      for (int j = 0; j < 4; ++j) {
        h[j]   = f2bf((bf2f(x[j])   - mu)*rs*gv0[j] + bv0[j]);
        h[j+4] = f2bf((bf2f(x[j+4]) - mu)*rs*gv1[j] + bv1[j]);
      }
      *(u16x8*)((char*)lA[buf] + swz(ar, ak8*16)) = h;
    }
  };

  #pragma unroll
  for (int i = 0; i < 8; ++i)
    gload16(Bt + (size_t)(br + i*64)*512 + bsrc, (char*)lB[0] + i*8192 + t*16);
  stageA(0, 0);
  __syncthreads();

  f32x4 acc[2][4] = {};
  int cur = 0;
  for (int k0 = 0; k0 < 512; k0 += 64) {
    if (k0 + 64 < 512) {
      #pragma unroll
      for (int i = 0; i < 8; ++i)
        gload16(Bt + (size_t)(br + i*64)*512 + k0 + 64 + bsrc, (char*)lB[cur^1] + i*8192 + t*16);
      stageA(cur^1, k0 + 64);
    }
    const char* lAc = (const char*)lA[cur];
    const char* lBc = (const char*)lB[cur];
    #pragma unroll
    for (int ks = 0; ks < 2; ++ks) {
      bf16x8 af[2], bfv[4];
      #pragma unroll
      for (int m = 0; m < 2; ++m)
        af[m] = *(const bf16x8*)(lAc + swz(m*16 + l15, ks*64 + lg*16));
      #pragma unroll
      for (int n = 0; n < 4; ++n)
        bfv[n] = *(const bf16x8*)(lBc + swz(wid*64 + n*16 + l15, ks*64 + lg*16));
      #pragma unroll
      for (int m = 0; m < 2; ++m)
        #pragma unroll
        for (int n = 0; n < 4; ++n)
          acc[m][n] = MFMA(af[m], bfv[n], acc[m][n]);
    }
    __syncthreads();
    cur ^= 1;
  }

  // ---- epilogue: G = H + relu(acc + bo); LN1 partials in-register ----
  float Gv[2][4][4];
  float sp[2][4] = {}, ssp[2][4] = {};
  #pragma unroll
  for (int n = 0; n < 4; ++n) {
    int colg = wid*64 + n*16 + l15;
    float bov = bo[colg];
    float g0c = g0[colg], b0c = b0[colg];
    #pragma unroll
    for (int m = 0; m < 2; ++m) {
      #pragma unroll
      for (int rr = 0; rr < 4; ++rr) {
        int rit = m*16 + lg*4 + rr;
        float H = (bf2f(ob[(size_t)(row0 + rit)*512 + colg]) - mu0[rit])*rs0[rit]*g0c + b0c;
        float G = H + fmaxf(acc[m][n][rr] + bov, 0.0f);
        Gv[m][n][rr] = G;
        sp[m][rr] += G;
        ssp[m][rr] += G*G;
      }
    }
  }
  #pragma unroll
  for (int msk = 1; msk < 16; msk <<= 1)
    #pragma unroll
    for (int m = 0; m < 2; ++m)
      #pragma unroll
      for (int rr = 0; rr < 4; ++rr) {
        sp[m][rr]  += __shfl_xor(sp[m][rr],  msk, 64);
        ssp[m][rr] += __shfl_xor(ssp[m][rr], msk, 64);
      }
  if (l15 == 0) {
    #pragma unroll
    for (int m = 0; m < 2; ++m)
      #pragma unroll
      for (int rr = 0; rr < 4; ++rr) {
        int rit = m*16 + lg*4 + rr;
        ps1[rit][wid] = sp[m][rr];
        ss1[rit][wid] = ssp[m][rr];
      }
  }
  __syncthreads();
  if (t < 32) {
    float s = 0.0f, ss = 0.0f;
    #pragma unroll
    for (int w = 0; w < 8; ++w) { s += ps1[t][w]; ss += ss1[t][w]; }
    float mu = s * (1.0f/512.0f);
    float var = ss * (1.0f/512.0f) - mu*mu;
    mu1[t] = mu; rs1[t] = rsqrtf(var + 1e-5f);
  }
  __syncthreads();
  #pragma unroll
  for (int n = 0; n < 4; ++n) {
    int colg = wid*64 + n*16 + l15;
    float g1c = g1[colg], b1c = b1[colg];
    #pragma unroll
    for (int m = 0; m < 2; ++m)
      #pragma unroll
      for (int rr = 0; rr < 4; ++rr) {
        int rit = m*16 + lg*4 + rr;
        out[(size_t)(row0 + rit)*512 + colg] =
            (Gv[m][n][rr] - mu1[rit])*rs1[rit]*g1c + b1c;
      }
  }
}

extern "C" void kernel_launch(void* const* d_in, const int* in_sizes, int n_in,
                              void* d_out, int out_size, void* d_ws, size_t ws_size,
                              hipStream_t stream)
{
  const float* Q   = (const float*)d_in[0];
  const float* K   = (const float*)d_in[1];
  const float* Wq  = (const float*)d_in[2];
  const float* bq  = (const float*)d_in[3];
  const float* Wk  = (const float*)d_in[4];
  const float* bk  = (const float*)d_in[5];
  const float* Wv  = (const float*)d_in[6];
  const float* bv  = (const float*)d_in[7];
  const float* Wo  = (const float*)d_in[8];
  const float* bo  = (const float*)d_in[9];
  const float* g0  = (const float*)d_in[10];
  const float* b0  = (const float*)d_in[11];
  const float* g1  = (const float*)d_in[12];
  const float* b1  = (const float*)d_in[13];

  char* ws = (char*)d_ws;
  // layout (MB): wt 0-2 | qbuf 2-10 | kbuf 10-18 | vt 18-26 | ob 26-34
  u16*   wt    = (u16*)(ws + 0);
  u16*   qbuf  = (u16*)(ws + (2u<<20));
  u16*   kbuf  = (u16*)(ws + (10u<<20));
  u16*   vt    = (u16*)(ws + (18u<<20));
  u16*   ob    = (u16*)(ws + (26u<<20));

  // 1. weight transpose+convert (Wq/bq scaled by 1/sqrt(512)*log2e)
  wprep_k<<<dim3(8, 8, 4), 256, 0, stream>>>(Wq, Wk, Wv, Wo, wt);
  // 2. projections: uniform 128x128 tiles, 768 blocks (Q | K | V-transposed)
  proj_k<<<768, 512, 0, stream>>>(Q, K, wt, bq, bk, bv, qbuf, kbuf, vt);
  // 3. attention, in-block KV-split + combine, XCD-swizzled grid -> ob (bf16, final)
  attn_k<<<512, 512, 0, stream>>>(qbuf, kbuf, vt, ob);
  // 4. fused tail: LN0 -> Wo GEMM + ReLU + residual -> LN1 -> out (fp32)
  tail_k<<<256, 512, 0, stream>>>(ob, wt + 3*262144, bo, g0, b0, g1, b1, (float*)d_out);
}

// Round 15
// 98.932 us; speedup vs baseline: 1.0839x; 1.0839x over previous
//
#include <hip/hip_runtime.h>

typedef float f32x4 __attribute__((ext_vector_type(4)));
typedef float f32x16 __attribute__((ext_vector_type(16)));
typedef __bf16 bf16x8 __attribute__((ext_vector_type(8)));
typedef unsigned short u16;
typedef unsigned int u32;
typedef u16 u16x8 __attribute__((ext_vector_type(8)));
typedef u16 u16x4 __attribute__((ext_vector_type(4)));
typedef u32 u32x4 __attribute__((ext_vector_type(4)));

#define SCALE2F (0.044194173824159216f * 1.4426950408889634f)   // 1/sqrt(512) * log2(e)
#define UNSCALE (1.0f / SCALE2F)

__device__ __forceinline__ u16 f2bf(float x){ return __builtin_bit_cast(u16, (__bf16)x); }
__device__ __forceinline__ float bf2f(u16 h){ unsigned u = ((unsigned)h) << 16; return __builtin_bit_cast(float, u); }
// XOR swizzle within a 128B row: involution, bijective per 128B wrap
__device__ __forceinline__ int swz(int r, int byteInRow){ return (r*128 + byteInRow) ^ ((r & 7) << 4); }
// async global->LDS, 16B per lane; LDS dest must be wave-uniform base + lane*16
__device__ __forceinline__ void gload16(const void* g, void* l) {
  __builtin_amdgcn_global_load_lds(
      (const __attribute__((address_space(1))) void*)g,
      (__attribute__((address_space(3))) void*)l, 16, 0, 0);
}
__device__ __forceinline__ u32 cvtpk(float lo, float hi_) {
  u32 r;
  asm("v_cvt_pk_bf16_f32 %0, %1, %2" : "=v"(r) : "v"(lo), "v"(hi_));
  return r;
}
// v_permlane32_swap_b32: a' = {a.lo32, b.lo32}, b' = {a.hi32, b.hi32}
__device__ __forceinline__ void swap32(u32 &a, u32 &b) {
  asm("v_permlane32_swap_b32 %0, %1" : "+v"(a), "+v"(b));
}

#define MFMA(a,b,c)   __builtin_amdgcn_mfma_f32_16x16x32_bf16((a),(b),(c),0,0,0)
#define MFMA32(a,b,c) __builtin_amdgcn_mfma_f32_32x32x16_bf16((a),(b),(c),0,0,0)

// ---------------- weight prep: Wt[n][k] = bf16(W[k][n] * sc), 512x512 x4 ----------------
__global__ __launch_bounds__(256) void wprep_k(
    const float* __restrict__ W0, const float* __restrict__ W1,
    const float* __restrict__ W2, const float* __restrict__ W3,
    u16* __restrict__ wt)
{
  __shared__ float tile[64][68];
  const float* Ws[4] = {W0, W1, W2, W3};
  const float* W = Ws[blockIdx.z];
  const float sc = (blockIdx.z == 0) ? SCALE2F : 1.0f;   // fold softmax scale into Wq
  u16* out = wt + (size_t)blockIdx.z * 512 * 512;
  int k0 = blockIdx.x * 64, n0 = blockIdx.y * 64;
  int t = threadIdx.x;
  #pragma unroll
  for (int i = 0; i < 2; ++i) {
    int c = t + i*256; int r = c >> 3, k8 = c & 7;
    const float* src = W + (size_t)(k0 + r)*512 + n0 + k8*8;
    *(f32x4*)&tile[r][k8*8]     = *(const f32x4*)src;
    *(f32x4*)&tile[r][k8*8 + 4] = *(const f32x4*)(src + 4);
  }
  __syncthreads();
  #pragma unroll
  for (int i = 0; i < 2; ++i) {
    int c = t + i*256; int r = c >> 3, k8 = c & 7;
    u16x8 h;
    #pragma unroll
    for (int j = 0; j < 8; ++j) h[j] = f2bf(tile[k8*8 + j][r] * sc);
    *(u16x8*)(out + (size_t)(n0 + r)*512 + k0 + k8*8) = h;
  }
}

// ---------------- fp32 -> bf16 cast for Q and K (proj A-panels are traffic-bound) -------
__global__ __launch_bounds__(256) void conv_k(
    const float* __restrict__ s0, const float* __restrict__ s1,
    u16* __restrict__ d0, u16* __restrict__ d1)
{
  const float* s = blockIdx.y ? s1 : s0;
  u16* d = blockIdx.y ? d1 : d0;
  size_t i = ((size_t)blockIdx.x * 256 + threadIdx.x) * 8;
  f32x4 a = *(const f32x4*)(s + i);
  f32x4 b = *(const f32x4*)(s + i + 4);
  u16x8 h;
  #pragma unroll
  for (int j = 0; j < 4; ++j) { h[j] = f2bf(a[j]); h[j+4] = f2bf(b[j]); }
  *(u16x8*)(d + i) = h;
}

// ---------------- projections: z=0 Q->qbuf; z=1 K->kbuf AND V->vt (A staged once) -------
// A now bf16 via gload16 (half the panel bytes; A-traffic was the measured bound, r14).
__global__ __launch_bounds__(512) void proj2_k(
    const u16* __restrict__ Qbf, const u16* __restrict__ Kbf,
    const u16* __restrict__ wt,
    const float* __restrict__ bq, const float* __restrict__ bk, const float* __restrict__ bv,
    u16* __restrict__ qbuf, u16* __restrict__ kbuf, u16* __restrict__ vt)
{
  __shared__ __align__(16) u16 lA[2][64*64];     // 16KB
  __shared__ __align__(16) u16 lB0[2][128*64];   // 32KB
  __shared__ __align__(16) u16 lB1[2][128*64];   // 32KB  (used only by z=1)
  int z = blockIdx.z;
  const u16*   A     = z ? Kbf : Qbf;
  const u16*   Bt0   = wt + (size_t)(z ? 1 : 0) * 262144;
  const u16*   Bt1   = wt + (size_t)2 * 262144;
  const float* bias0 = z ? bk : bq;
  const float bscale = z ? 1.0f : SCALE2F;
  int row0 = blockIdx.x * 64, col0 = blockIdx.y * 128;
  int t = threadIdx.x, lane = t & 63, wid = t >> 6;
  int wr = wid >> 2, wc = wid & 3;              // 2x4 waves, 32x32 out each
  int l15 = lane & 15, lg = lane >> 4;
  int ar = t >> 3;
  int asrc = ((t & 7) ^ (ar & 7)) << 3;         // inverse-swizzled source col (elements)
  const u16* Arow  = A + (size_t)row0 * 512;
  const u16* B0row = Bt0 + (size_t)col0 * 512;
  const u16* B1row = Bt1 + (size_t)col0 * 512;

  f32x4 acc0[2][2] = {}, acc1[2][2] = {};

#define STG(buf, k0)                                                                         \
  gload16(Arow + (size_t)ar*512 + (k0) + asrc, (char*)lA[buf] + t*16);                       \
  gload16(B0row + (size_t)ar*512 + (k0) + asrc, (char*)lB0[buf] + t*16);                     \
  gload16(B0row + (size_t)(ar + 64)*512 + (k0) + asrc, (char*)lB0[buf] + 8192 + t*16);       \
  if (z) {                                                                                   \
    gload16(B1row + (size_t)ar*512 + (k0) + asrc, (char*)lB1[buf] + t*16);                   \
    gload16(B1row + (size_t)(ar + 64)*512 + (k0) + asrc, (char*)lB1[buf] + 8192 + t*16);     \
  }

  STG(0, 0);
  __syncthreads();

  int cur = 0;
  for (int k0 = 0; k0 < 512; k0 += 64) {
    if (k0 + 64 < 512) { STG(cur^1, k0 + 64); }
    const char* lAc = (const char*)lA[cur];
    const char* lB0c = (const char*)lB0[cur];
    const char* lB1c = (const char*)lB1[cur];
    #pragma unroll
    for (int ks = 0; ks < 2; ++ks) {
      bf16x8 af[2], b0f[2], b1f[2];
      #pragma unroll
      for (int m = 0; m < 2; ++m)
        af[m] = *(const bf16x8*)(lAc + swz(wr*32 + m*16 + l15, ks*64 + lg*16));
      #pragma unroll
      for (int n = 0; n < 2; ++n) {
        int rb = wc*32 + n*16 + l15;
        b0f[n] = *(const bf16x8*)(lB0c + swz(rb, ks*64 + lg*16));
        if (z) b1f[n] = *(const bf16x8*)(lB1c + swz(rb, ks*64 + lg*16));
      }
      #pragma unroll
      for (int m = 0; m < 2; ++m)
        #pragma unroll
        for (int n = 0; n < 2; ++n) {
          acc0[m][n] = MFMA(af[m], b0f[n], acc0[m][n]);
          if (z) acc1[m][n] = MFMA(af[m], b1f[n], acc1[m][n]);
        }
    }
    __syncthreads();
    cur ^= 1;
  }
#undef STG

  // epilogue: acc0 -> qbuf (z=0) or kbuf (z=1); acc1 -> vt transposed (z=1 only)
  u16* out0 = z ? kbuf : qbuf;
  #pragma unroll
  for (int m = 0; m < 2; ++m) {
    int rowg = row0 + wr*32 + m*16 + lg*4;
    #pragma unroll
    for (int n = 0; n < 2; ++n) {
      int colg = col0 + wc*32 + n*16 + l15;
      float bvv = bias0[colg] * bscale;
      #pragma unroll
      for (int r = 0; r < 4; ++r)
        out0[(size_t)(rowg + r)*512 + colg] = f2bf(acc0[m][n][r] + bvv);
    }
  }
  if (z) {
    #pragma unroll
    for (int m = 0; m < 2; ++m) {
      int rowg = row0 + wr*32 + m*16 + lg*4;
      int b = rowg >> 11, ntok = rowg & 2047;
      #pragma unroll
      for (int n = 0; n < 2; ++n) {
        int colg = col0 + wc*32 + n*16 + l15;
        float bvv = bv[colg];
        u16x4 hv;
        #pragma unroll
        for (int r = 0; r < 4; ++r) hv[r] = f2bf(acc1[m][n][r] + bvv);
        *(u16x4*)(vt + ((size_t)b*512 + colg)*2048 + ntok) = hv;
      }
    }
  }
}

// ---------------- flash attention: 8 waves = 4 q-waves x 2 KV-halves, in-block combine --
// 1D grid with XCD-aware decode (r14: FETCH 74->12.8 MB).
__device__ __forceinline__ void mk_pb(const f32x16& s, float& ps, bf16x8& f0, bf16x8& f1) {
  float p[16];
  #pragma unroll
  for (int r = 0; r < 16; ++r) p[r] = __builtin_amdgcn_exp2f(s[r]);
  float t0 = (p[0] + p[1])  + (p[2] + p[3]);
  float t1 = (p[4] + p[5])  + (p[6] + p[7]);
  float t2 = (p[8] + p[9])  + (p[10] + p[11]);
  float t3 = (p[12] + p[13]) + (p[14] + p[15]);
  ps += (t0 + t1) + (t2 + t3);
  u32 a0 = cvtpk(p[0],  p[1]),  b0 = cvtpk(p[4],  p[5]);
  u32 a1 = cvtpk(p[2],  p[3]),  b1 = cvtpk(p[6],  p[7]);
  swap32(a0, b0); swap32(a1, b1);
  u32 a2 = cvtpk(p[8],  p[9]),  b2 = cvtpk(p[12], p[13]);
  u32 a3 = cvtpk(p[10], p[11]), b3 = cvtpk(p[14], p[15]);
  swap32(a2, b2); swap32(a3, b3);
  u32x4 w0 = {a0, a1, b0, b1};
  u32x4 w1 = {a2, a3, b2, b3};
  f0 = __builtin_bit_cast(bf16x8, w0);
  f1 = __builtin_bit_cast(bf16x8, w1);
}

__global__ __launch_bounds__(512, 4) void attn_k(
    const u16* __restrict__ qb, const u16* __restrict__ kb,
    const u16* __restrict__ vt, u16* __restrict__ ob)
{
  __shared__ __align__(16) char smem[65536];   // lK: 4x8KB | lV: 4x8KB; combine reuses lK

  int t = threadIdx.x, lane = t & 63, wid = t >> 6;
  // XCD-aware decode of 1D block id (bijective over 512)
  int j = blockIdx.x;
  int xcd = j & 7, slot = j >> 3;
  int qx = slot & 15;
  int bh = ((slot >> 4) << 3) | xcd;
  int b = bh >> 3, h = bh & 7;
  int half = wid >> 2;                         // KV half (0: 0-1023, 1: 1024-2047)
  int qw = wid & 3;
  int q0 = qx * 128 + qw * 32;                 // 4 q-waves x 32 rows
  int l31 = lane & 31, hi = lane >> 5;

  const u16* kbase = kb + ((size_t)b*2048)*512 + h*64;
  const u16* vbase = vt + ((size_t)b*512 + h*64)*2048;

  int sr = t >> 3;                                   // 0..63
  int ssrc = ((t & 7) ^ (sr & 7)) << 3;              // inverse-swizzled src col (elements)

#define LKB(hf, bf) (smem + ((hf)*2 + (bf))*8192)
#define LVB(hf, bf) (smem + 32768 + ((hf)*2 + (bf))*8192)
#define STAGE(buf, off)                                                           \
  gload16(kbase + (size_t)((off) + sr)*512 + ssrc,        LKB(0,buf) + t*16);     \
  gload16(kbase + (size_t)((off) + 1024 + sr)*512 + ssrc, LKB(1,buf) + t*16);     \
  gload16(vbase + (size_t)sr*2048 + (off) + ssrc,         LVB(0,buf) + t*16);     \
  gload16(vbase + (size_t)sr*2048 + (off) + 1024 + ssrc,  LVB(1,buf) + t*16);

  bf16x8 aq[4];
  {
    const u16* qp = qb + ((size_t)(b*2048 + q0 + l31))*512 + h*64 + hi*8;
    #pragma unroll
    for (int ks = 0; ks < 4; ++ks) aq[ks] = *(const bf16x8*)(qp + ks*16);
  }

  f32x16 acc[2] = {};
  float ps = 0.0f;

  STAGE(0, 0);
  __syncthreads();

  int cur = 0;
  for (int i = 0; i < 16; ++i) {
    if (i + 1 < 16) { STAGE(cur^1, (i+1)*64); }
    const char* lKc = LKB(half, cur);
    const char* lVc = LVB(half, cur);
    bf16x8 pb[4];
    #pragma unroll
    for (int n = 0; n < 2; ++n) {
      f32x16 s = {};
      #pragma unroll
      for (int ks = 0; ks < 4; ++ks) {
        bf16x8 kf = *(const bf16x8*)(lKc + swz(n*32 + l31, ks*32 + hi*16));
        s = MFMA32(kf, aq[ks], s);
      }
      mk_pb(s, ps, pb[2*n], pb[2*n+1]);
    }
    #pragma unroll
    for (int m = 0; m < 2; ++m)
      #pragma unroll
      for (int ks = 0; ks < 4; ++ks) {
        bf16x8 vf = *(const bf16x8*)(lVc + swz(m*32 + l31, ks*32 + hi*16));
        acc[m] = MFMA32(vf, pb[ks], acc[m]);
      }
    __syncthreads();
    cur ^= 1;
  }
#undef STAGE

  // ---- in-block combine: half-1 -> LDS (pitch 68 f32, region 2208 f32 per q-wave) ----
  ps += __shfl_xor(ps, 32, 64);
  float* cb = (float*)smem;
  if (half == 1) {
    float* dst = cb + qw * 2208;
    #pragma unroll
    for (int m = 0; m < 2; ++m)
      #pragma unroll
      for (int rq = 0; rq < 4; ++rq) {
        f32x4 v = {acc[m][rq*4], acc[m][rq*4+1], acc[m][rq*4+2], acc[m][rq*4+3]};
        *(f32x4*)(dst + l31*68 + m*32 + rq*8 + hi*4) = v;
      }
    if (hi == 0) dst[2176 + l31] = ps;
  }
  __syncthreads();
  if (half == 0) {
    const float* src = cb + qw * 2208;
    float inv = 1.0f / (ps + src[2176 + l31]);
    u16* obase = ob + ((size_t)(b*2048 + q0 + l31))*512 + h*64;
    const u16* qrb = qb + ((size_t)(b*2048 + q0 + l31))*512 + h*64;
    #pragma unroll
    for (int m = 0; m < 2; ++m)
      #pragma unroll
      for (int rq = 0; rq < 4; ++rq) {
        f32x4 other = *(const f32x4*)(src + l31*68 + m*32 + rq*8 + hi*4);
        u16x4 qr4 = *(const u16x4*)(qrb + m*32 + rq*8 + hi*4);
        u16x4 o4;
        #pragma unroll
        for (int e = 0; e < 4; ++e)
          o4[e] = f2bf((acc[m][rq*4 + e] + other[e])*inv + bf2f(qr4[e])*UNSCALE);
        *(u16x4*)(obase + m*32 + rq*8 + hi*4) = o4;
      }
  }
}

// ---------------- fused tail: LN0 (on-the-fly) -> Wo GEMM + ReLU + residual -> LN1 ------
__global__ __launch_bounds__(512) void tail_k(
    const u16* __restrict__ ob, const u16* __restrict__ Bt,
    const float* __restrict__ bo,
    const float* __restrict__ g0, const float* __restrict__ b0,
    const float* __restrict__ g1, const float* __restrict__ b1,
    float* __restrict__ out)
{
  __shared__ __align__(16) u16 lA[2][32*64];     // 4KB each
  __shared__ __align__(16) u16 lB[2][512*64];    // 64KB each
  __shared__ float mu0[32], rs0[32], mu1[32], rs1[32];
  __shared__ float ps1[32][8], ss1[32][8];

  int row0 = blockIdx.x * 32;
  int t = threadIdx.x, lane = t & 63, wid = t >> 6;
  int l15 = lane & 15, lg = lane >> 4;

  // ---- LN0 stats: 16 threads per row, 32 elems each ----
  {
    int r = t >> 4, c0 = (t & 15) * 32;
    const u16* xp = ob + (size_t)(row0 + r)*512 + c0;
    float s = 0.0f, ss = 0.0f;
    #pragma unroll
    for (int j = 0; j < 4; ++j) {
      u16x8 v = *(const u16x8*)(xp + j*8);
      #pragma unroll
      for (int e = 0; e < 8; ++e) { float f = bf2f(v[e]); s += f; ss += f*f; }
    }
    #pragma unroll
    for (int m = 1; m < 16; m <<= 1) { s += __shfl_xor(s, m, 64); ss += __shfl_xor(ss, m, 64); }
    if ((t & 15) == 0) {
      float mu = s * (1.0f/512.0f);
      float var = ss * (1.0f/512.0f) - mu*mu;
      mu0[r] = mu; rs0[r] = rsqrtf(var + 1e-5f);
    }
  }
  __syncthreads();

  int ar = t >> 3, ak8 = t & 7;
  int br = t >> 3;
  int bsrc = ((t & 7) ^ (br & 7)) << 3;

  auto stageA = [&](int buf, int k0) {
    if (t < 256) {
      u16x8 x = *(const u16x8*)(ob + (size_t)(row0 + ar)*512 + k0 + ak8*8);
      f32x4 gv0 = *(const f32x4*)(g0 + k0 + ak8*8);
      f32x4 gv1 = *(const f32x4*)(g0 + k0 + ak8*8 + 4);
      f32x4 bv0 = *(const f32x4*)(b0 + k0 + ak8*8);
      f32x4 bv1 = *(const f32x4*)(b0 + k0 + ak8*8 + 4);
      float mu = mu0[ar], rs = rs0[ar];
      u16x8 h;
      #pragma unroll
      for (int j = 0; j < 4; ++j) {
        h[j]   = f2bf((bf2f(x[j])   - mu)*rs*gv0[j] + bv0[j]);
        h[j+4] = f2bf((bf2f(x[j+4]) - mu)*rs*gv1[j] + bv1[j]);
      }
      *(u16x8*)((char*)lA[buf] + swz(ar, ak8*16)) = h;
    }
  };

  #pragma unroll
  for (int i = 0; i < 8; ++i)
    gload16(Bt + (size_t)(br + i*64)*512 + bsrc, (char*)lB[0] + i*8192 + t*16);
  stageA(0, 0);
  __syncthreads();

  f32x4 acc[2][4] = {};
  int cur = 0;
  for (int k0 = 0; k0 < 512; k0 += 64) {
    if (k0 + 64 < 512) {
      #pragma unroll
      for (int i = 0; i < 8; ++i)
        gload16(Bt + (size_t)(br + i*64)*512 + k0 + 64 + bsrc, (char*)lB[cur^1] + i*8192 + t*16);
      stageA(cur^1, k0 + 64);
    }
    const char* lAc = (const char*)lA[cur];
    const char* lBc = (const char*)lB[cur];
    #pragma unroll
    for (int ks = 0; ks < 2; ++ks) {
      bf16x8 af[2], bfv[4];
      #pragma unroll
      for (int m = 0; m < 2; ++m)
        af[m] = *(const bf16x8*)(lAc + swz(m*16 + l15, ks*64 + lg*16));
      #pragma unroll
      for (int n = 0; n < 4; ++n)
        bfv[n] = *(const bf16x8*)(lBc + swz(wid*64 + n*16 + l15, ks*64 + lg*16));
      #pragma unroll
      for (int m = 0; m < 2; ++m)
        #pragma unroll
        for (int n = 0; n < 4; ++n)
          acc[m][n] = MFMA(af[m], bfv[n], acc[m][n]);
    }
    __syncthreads();
    cur ^= 1;
  }

  // ---- epilogue: G = H + relu(acc + bo); LN1 partials in-register ----
  float Gv[2][4][4];
  float sp[2][4] = {}, ssp[2][4] = {};
  #pragma unroll
  for (int n = 0; n < 4; ++n) {
    int colg = wid*64 + n*16 + l15;
    float bov = bo[colg];
    float g0c = g0[colg], b0c = b0[colg];
    #pragma unroll
    for (int m = 0; m < 2; ++m) {
      #pragma unroll
      for (int rr = 0; rr < 4; ++rr) {
        int rit = m*16 + lg*4 + rr;
        float H = (bf2f(ob[(size_t)(row0 + rit)*512 + colg]) - mu0[rit])*rs0[rit]*g0c + b0c;
        float G = H + fmaxf(acc[m][n][rr] + bov, 0.0f);
        Gv[m][n][rr] = G;
        sp[m][rr] += G;
        ssp[m][rr] += G*G;
      }
    }
  }
  #pragma unroll
  for (int msk = 1; msk < 16; msk <<= 1)
    #pragma unroll
    for (int m = 0; m < 2; ++m)
      #pragma unroll
      for (int rr = 0; rr < 4; ++rr) {
        sp[m][rr]  += __shfl_xor(sp[m][rr],  msk, 64);
        ssp[m][rr] += __shfl_xor(ssp[m][rr], msk, 64);
      }
  if (l15 == 0) {
    #pragma unroll
    for (int m = 0; m < 2; ++m)
      #pragma unroll
      for (int rr = 0; rr < 4; ++rr) {
        int rit = m*16 + lg*4 + rr;
        ps1[rit][wid] = sp[m][rr];
        ss1[rit][wid] = ssp[m][rr];
      }
  }
  __syncthreads();
  if (t < 32) {
    float s = 0.0f, ss = 0.0f;
    #pragma unroll
    for (int w = 0; w < 8; ++w) { s += ps1[t][w]; ss += ss1[t][w]; }
    float mu = s * (1.0f/512.0f);
    float var = ss * (1.0f/512.0f) - mu*mu;
    mu1[t] = mu; rs1[t] = rsqrtf(var + 1e-5f);
  }
  __syncthreads();
  #pragma unroll
  for (int n = 0; n < 4; ++n) {
    int colg = wid*64 + n*16 + l15;
    float g1c = g1[colg], b1c = b1[colg];
    #pragma unroll
    for (int m = 0; m < 2; ++m)
      #pragma unroll
      for (int rr = 0; rr < 4; ++rr) {
        int rit = m*16 + lg*4 + rr;
        out[(size_t)(row0 + rit)*512 + colg] =
            (Gv[m][n][rr] - mu1[rit])*rs1[rit]*g1c + b1c;
      }
  }
}

extern "C" void kernel_launch(void* const* d_in, const int* in_sizes, int n_in,
                              void* d_out, int out_size, void* d_ws, size_t ws_size,
                              hipStream_t stream)
{
  const float* Q   = (const float*)d_in[0];
  const float* K   = (const float*)d_in[1];
  const float* Wq  = (const float*)d_in[2];
  const float* bq  = (const float*)d_in[3];
  const float* Wk  = (const float*)d_in[4];
  const float* bk  = (const float*)d_in[5];
  const float* Wv  = (const float*)d_in[6];
  const float* bv  = (const float*)d_in[7];
  const float* Wo  = (const float*)d_in[8];
  const float* bo  = (const float*)d_in[9];
  const float* g0  = (const float*)d_in[10];
  const float* b0  = (const float*)d_in[11];
  const float* g1  = (const float*)d_in[12];
  const float* b1  = (const float*)d_in[13];

  char* ws = (char*)d_ws;
  // layout (MB): wt 0-2 | qbuf 2-10 | kbuf 10-18 | vt 18-26 | ob 26-34 | Qbf 34-42.4 | Kbf 43-51.4
  u16*   wt    = (u16*)(ws + 0);
  u16*   qbuf  = (u16*)(ws + (2u<<20));
  u16*   kbuf  = (u16*)(ws + (10u<<20));
  u16*   vt    = (u16*)(ws + (18u<<20));
  u16*   ob    = (u16*)(ws + (26u<<20));
  u16*   Qbf   = (u16*)(ws + (34u<<20));
  u16*   Kbf   = (u16*)(ws + (43u<<20));

  // 1. weight transpose+convert (Wq/bq scaled by 1/sqrt(512)*log2e)
  wprep_k<<<dim3(8, 8, 4), 256, 0, stream>>>(Wq, Wk, Wv, Wo, wt);
  // 2. cast Q, K to bf16 (halves proj2's A-panel re-read bytes — the measured bound)
  conv_k<<<dim3(2048, 2), 256, 0, stream>>>(Q, K, Qbf, Kbf);
  // 3. projections: z=0 Q; z=1 K+V fused (K staged once), V written pre-transposed
  proj2_k<<<dim3(128, 4, 2), 512, 0, stream>>>(Qbf, Kbf, wt, bq, bk, bv, qbuf, kbuf, vt);
  // 4. attention, in-block KV-split + combine, XCD-swizzled grid -> ob (bf16, final)
  attn_k<<<512, 512, 0, stream>>>(qbuf, kbuf, vt, ob);
  // 5. fused tail: LN0 -> Wo GEMM + ReLU + residual -> LN1 -> out (fp32)
  tail_k<<<256, 512, 0, stream>>>(ob, wt + 3*262144, bo, g0, b0, g1, b1, (float*)d_out);
}

// Round 16
// 94.584 us; speedup vs baseline: 1.1337x; 1.0460x over previous
//
#include <hip/hip_runtime.h>

typedef float f32x4 __attribute__((ext_vector_type(4)));
typedef float f32x16 __attribute__((ext_vector_type(16)));
typedef __bf16 bf16x8 __attribute__((ext_vector_type(8)));
typedef unsigned short u16;
typedef unsigned int u32;
typedef u16 u16x8 __attribute__((ext_vector_type(8)));
typedef u16 u16x4 __attribute__((ext_vector_type(4)));
typedef u32 u32x4 __attribute__((ext_vector_type(4)));

#define SCALE2F (0.044194173824159216f * 1.4426950408889634f)   // 1/sqrt(512) * log2(e)
#define UNSCALE (1.0f / SCALE2F)

__device__ __forceinline__ u16 f2bf(float x){ return __builtin_bit_cast(u16, (__bf16)x); }
__device__ __forceinline__ float bf2f(u16 h){ unsigned u = ((unsigned)h) << 16; return __builtin_bit_cast(float, u); }
// XOR swizzle within a 128B row: involution, bijective per 128B wrap
__device__ __forceinline__ int swz(int r, int byteInRow){ return (r*128 + byteInRow) ^ ((r & 7) << 4); }
// async global->LDS, 16B per lane; LDS dest must be wave-uniform base + lane*16
__device__ __forceinline__ void gload16(const void* g, void* l) {
  __builtin_amdgcn_global_load_lds(
      (const __attribute__((address_space(1))) void*)g,
      (__attribute__((address_space(3))) void*)l, 16, 0, 0);
}
__device__ __forceinline__ u32 cvtpk(float lo, float hi_) {
  u32 r;
  asm("v_cvt_pk_bf16_f32 %0, %1, %2" : "=v"(r) : "v"(lo), "v"(hi_));
  return r;
}
// v_permlane32_swap_b32: a' = {a.lo32, b.lo32}, b' = {a.hi32, b.hi32}
__device__ __forceinline__ void swap32(u32 &a, u32 &b) {
  asm("v_permlane32_swap_b32 %0, %1" : "+v"(a), "+v"(b));
}

#define MFMA(a,b,c)   __builtin_amdgcn_mfma_f32_16x16x32_bf16((a),(b),(c),0,0,0)
#define MFMA32(a,b,c) __builtin_amdgcn_mfma_f32_32x32x16_bf16((a),(b),(c),0,0,0)

// ---------------- weight prep: Wt[n][k] = bf16(W[k][n] * sc), 512x512 x4 ----------------
__global__ __launch_bounds__(256) void wprep_k(
    const float* __restrict__ W0, const float* __restrict__ W1,
    const float* __restrict__ W2, const float* __restrict__ W3,
    u16* __restrict__ wt)
{
  __shared__ float tile[64][68];
  const float* Ws[4] = {W0, W1, W2, W3};
  const float* W = Ws[blockIdx.z];
  const float sc = (blockIdx.z == 0) ? SCALE2F : 1.0f;   // fold softmax scale into Wq
  u16* out = wt + (size_t)blockIdx.z * 512 * 512;
  int k0 = blockIdx.x * 64, n0 = blockIdx.y * 64;
  int t = threadIdx.x;
  #pragma unroll
  for (int i = 0; i < 2; ++i) {
    int c = t + i*256; int r = c >> 3, k8 = c & 7;
    const float* src = W + (size_t)(k0 + r)*512 + n0 + k8*8;
    *(f32x4*)&tile[r][k8*8]     = *(const f32x4*)src;
    *(f32x4*)&tile[r][k8*8 + 4] = *(const f32x4*)(src + 4);
  }
  __syncthreads();
  #pragma unroll
  for (int i = 0; i < 2; ++i) {
    int c = t + i*256; int r = c >> 3, k8 = c & 7;
    u16x8 h;
    #pragma unroll
    for (int j = 0; j < 8; ++j) h[j] = f2bf(tile[k8*8 + j][r] * sc);
    *(u16x8*)(out + (size_t)(n0 + r)*512 + k0 + k8*8) = h;
  }
}

// ---------------- projections (r13 structure + XCD-grouped grid) ------------------------
// z=0: Q->qbuf; z=1: K->kbuf AND V->vt (A staged once). fp32 A reg-staged -> bf16 LDS.
// 1D grid of 1024; decode puts the 4 col-panel siblings (same A row-tile) on ONE XCD
// (ids differ by multiples of 8 under round-robin dispatch) -> A fetched once per XCD L2.
__global__ __launch_bounds__(512) void proj2_k(
    const float* __restrict__ Qin, const float* __restrict__ Kin,
    const u16* __restrict__ wt,
    const float* __restrict__ bq, const float* __restrict__ bk, const float* __restrict__ bv,
    u16* __restrict__ qbuf, u16* __restrict__ kbuf, u16* __restrict__ vt)
{
  __shared__ __align__(16) u16 lA[2][64*64];     // 16KB
  __shared__ __align__(16) u16 lB0[2][128*64];   // 32KB
  __shared__ __align__(16) u16 lB1[2][128*64];   // 32KB  (used only by z=1)
  // XCD-aware decode (bijective over 1024)
  int j = blockIdx.x;
  int xcd = j & 7, s = j >> 3;          // s: 0..127
  int py = s & 3;                        // col panel 0..3
  int z  = (s >> 2) & 1;                 // 0: Q, 1: K+V
  int px = (s >> 3) * 8 + xcd;           // row tile 0..127
  const float* A     = z ? Kin : Qin;
  const u16*   Bt0   = wt + (size_t)(z ? 1 : 0) * 262144;
  const u16*   Bt1   = wt + (size_t)2 * 262144;
  const float* bias0 = z ? bk : bq;
  const float bscale = z ? 1.0f : SCALE2F;
  int row0 = px * 64, col0 = py * 128;
  int t = threadIdx.x, lane = t & 63, wid = t >> 6;
  int wr = wid >> 2, wc = wid & 3;              // 2x4 waves, 32x32 out each
  int l15 = lane & 15, lg = lane >> 4;
  int ar = t >> 3, ak8 = t & 7;
  int br = t >> 3;
  int bsrc = ((t & 7) ^ (br & 7)) << 3;         // inverse-swizzled source col (elements)
  const float* Arow = A + (size_t)row0 * 512;
  const u16*   B0row = Bt0 + (size_t)col0 * 512;
  const u16*   B1row = Bt1 + (size_t)col0 * 512;

  f32x4 acc0[2][2] = {}, acc1[2][2] = {};

  #pragma unroll
  for (int i = 0; i < 2; ++i)
    gload16(B0row + (size_t)(br + i*64)*512 + bsrc, (char*)lB0[0] + i*8192 + t*16);
  if (z) {
    #pragma unroll
    for (int i = 0; i < 2; ++i)
      gload16(B1row + (size_t)(br + i*64)*512 + bsrc, (char*)lB1[0] + i*8192 + t*16);
  }
  {
    const float* src = Arow + (size_t)ar*512 + ak8*8;
    f32x4 x0 = *(const f32x4*)src;
    f32x4 x1 = *(const f32x4*)(src + 4);
    u16x8 h;
    #pragma unroll
    for (int jj = 0; jj < 4; ++jj) { h[jj] = f2bf(x0[jj]); h[jj+4] = f2bf(x1[jj]); }
    *(u16x8*)((char*)lA[0] + swz(ar, ak8*16)) = h;
  }
  __syncthreads();

  int cur = 0;
  for (int k0 = 0; k0 < 512; k0 += 64) {
    bool pf = (k0 + 64 < 512);
    f32x4 px0, px1;
    if (pf) {
      #pragma unroll
      for (int i = 0; i < 2; ++i)
        gload16(B0row + (size_t)(br + i*64)*512 + k0 + 64 + bsrc, (char*)lB0[cur^1] + i*8192 + t*16);
      if (z) {
        #pragma unroll
        for (int i = 0; i < 2; ++i)
          gload16(B1row + (size_t)(br + i*64)*512 + k0 + 64 + bsrc, (char*)lB1[cur^1] + i*8192 + t*16);
      }
      const float* src = Arow + (size_t)ar*512 + k0 + 64 + ak8*8;
      px0 = *(const f32x4*)src;
      px1 = *(const f32x4*)(src + 4);
    }
    const char* lAc = (const char*)lA[cur];
    const char* lB0c = (const char*)lB0[cur];
    const char* lB1c = (const char*)lB1[cur];
    #pragma unroll
    for (int ks = 0; ks < 2; ++ks) {
      bf16x8 af[2], b0f[2], b1f[2];
      #pragma unroll
      for (int m = 0; m < 2; ++m)
        af[m] = *(const bf16x8*)(lAc + swz(wr*32 + m*16 + l15, ks*64 + lg*16));
      #pragma unroll
      for (int n = 0; n < 2; ++n) {
        int rb = wc*32 + n*16 + l15;
        b0f[n] = *(const bf16x8*)(lB0c + swz(rb, ks*64 + lg*16));
        if (z) b1f[n] = *(const bf16x8*)(lB1c + swz(rb, ks*64 + lg*16));
      }
      #pragma unroll
      for (int m = 0; m < 2; ++m)
        #pragma unroll
        for (int n = 0; n < 2; ++n) {
          acc0[m][n] = MFMA(af[m], b0f[n], acc0[m][n]);
          if (z) acc1[m][n] = MFMA(af[m], b1f[n], acc1[m][n]);
        }
    }
    if (pf) {
      u16x8 h;
      #pragma unroll
      for (int jj = 0; jj < 4; ++jj) { h[jj] = f2bf(px0[jj]); h[jj+4] = f2bf(px1[jj]); }
      *(u16x8*)((char*)lA[cur^1] + swz(ar, ak8*16)) = h;
    }
    __syncthreads();
    cur ^= 1;
  }

  // epilogue: acc0 -> qbuf (z=0) or kbuf (z=1); acc1 -> vt transposed (z=1 only)
  u16* out0 = z ? kbuf : qbuf;
  #pragma unroll
  for (int m = 0; m < 2; ++m) {
    int rowg = row0 + wr*32 + m*16 + lg*4;
    #pragma unroll
    for (int n = 0; n < 2; ++n) {
      int colg = col0 + wc*32 + n*16 + l15;
      float bvv = bias0[colg] * bscale;
      #pragma unroll
      for (int r = 0; r < 4; ++r)
        out0[(size_t)(rowg + r)*512 + colg] = f2bf(acc0[m][n][r] + bvv);
    }
  }
  if (z) {
    #pragma unroll
    for (int m = 0; m < 2; ++m) {
      int rowg = row0 + wr*32 + m*16 + lg*4;
      int b = rowg >> 11, ntok = rowg & 2047;
      #pragma unroll
      for (int n = 0; n < 2; ++n) {
        int colg = col0 + wc*32 + n*16 + l15;
        float bvv = bv[colg];
        u16x4 hv;
        #pragma unroll
        for (int r = 0; r < 4; ++r) hv[r] = f2bf(acc1[m][n][r] + bvv);
        *(u16x4*)(vt + ((size_t)b*512 + colg)*2048 + ntok) = hv;
      }
    }
  }
}

// ---------------- flash attention: 8 waves = 4 q-waves x 2 KV-halves, in-block combine --
// 1D grid with XCD-aware decode (verified r14/r15: FETCH 74->12.8 MB).
__device__ __forceinline__ void mk_pb(const f32x16& s, float& ps, bf16x8& f0, bf16x8& f1) {
  float p[16];
  #pragma unroll
  for (int r = 0; r < 16; ++r) p[r] = __builtin_amdgcn_exp2f(s[r]);
  float t0 = (p[0] + p[1])  + (p[2] + p[3]);
  float t1 = (p[4] + p[5])  + (p[6] + p[7]);
  float t2 = (p[8] + p[9])  + (p[10] + p[11]);
  float t3 = (p[12] + p[13]) + (p[14] + p[15]);
  ps += (t0 + t1) + (t2 + t3);
  u32 a0 = cvtpk(p[0],  p[1]),  b0 = cvtpk(p[4],  p[5]);
  u32 a1 = cvtpk(p[2],  p[3]),  b1 = cvtpk(p[6],  p[7]);
  swap32(a0, b0); swap32(a1, b1);
  u32 a2 = cvtpk(p[8],  p[9]),  b2 = cvtpk(p[12], p[13]);
  u32 a3 = cvtpk(p[10], p[11]), b3 = cvtpk(p[14], p[15]);
  swap32(a2, b2); swap32(a3, b3);
  u32x4 w0 = {a0, a1, b0, b1};
  u32x4 w1 = {a2, a3, b2, b3};
  f0 = __builtin_bit_cast(bf16x8, w0);
  f1 = __builtin_bit_cast(bf16x8, w1);
}

__global__ __launch_bounds__(512, 4) void attn_k(
    const u16* __restrict__ qb, const u16* __restrict__ kb,
    const u16* __restrict__ vt, u16* __restrict__ ob)
{
  __shared__ __align__(16) char smem[65536];   // lK: 4x8KB | lV: 4x8KB; combine reuses lK

  int t = threadIdx.x, lane = t & 63, wid = t >> 6;
  // XCD-aware decode of 1D block id (bijective over 512)
  int j = blockIdx.x;
  int xcd = j & 7, slot = j >> 3;
  int qx = slot & 15;
  int bh = ((slot >> 4) << 3) | xcd;
  int b = bh >> 3, h = bh & 7;
  int half = wid >> 2;                         // KV half (0: 0-1023, 1: 1024-2047)
  int qw = wid & 3;
  int q0 = qx * 128 + qw * 32;                 // 4 q-waves x 32 rows
  int l31 = lane & 31, hi = lane >> 5;

  const u16* kbase = kb + ((size_t)b*2048)*512 + h*64;
  const u16* vbase = vt + ((size_t)b*512 + h*64)*2048;

  int sr = t >> 3;                                   // 0..63
  int ssrc = ((t & 7) ^ (sr & 7)) << 3;              // inverse-swizzled src col (elements)

#define LKB(hf, bf) (smem + ((hf)*2 + (bf))*8192)
#define LVB(hf, bf) (smem + 32768 + ((hf)*2 + (bf))*8192)
#define STAGE(buf, off)                                                           \
  gload16(kbase + (size_t)((off) + sr)*512 + ssrc,        LKB(0,buf) + t*16);     \
  gload16(kbase + (size_t)((off) + 1024 + sr)*512 + ssrc, LKB(1,buf) + t*16);     \
  gload16(vbase + (size_t)sr*2048 + (off) + ssrc,         LVB(0,buf) + t*16);     \
  gload16(vbase + (size_t)sr*2048 + (off) + 1024 + ssrc,  LVB(1,buf) + t*16);

  bf16x8 aq[4];
  {
    const u16* qp = qb + ((size_t)(b*2048 + q0 + l31))*512 + h*64 + hi*8;
    #pragma unroll
    for (int ks = 0; ks < 4; ++ks) aq[ks] = *(const bf16x8*)(qp + ks*16);
  }

  f32x16 acc[2] = {};
  float ps = 0.0f;

  STAGE(0, 0);
  __syncthreads();

  int cur = 0;
  for (int i = 0; i < 16; ++i) {
    if (i + 1 < 16) { STAGE(cur^1, (i+1)*64); }
    const char* lKc = LKB(half, cur);
    const char* lVc = LVB(half, cur);
    bf16x8 pb[4];
    #pragma unroll
    for (int n = 0; n < 2; ++n) {
      f32x16 s = {};
      #pragma unroll
      for (int ks = 0; ks < 4; ++ks) {
        bf16x8 kf = *(const bf16x8*)(lKc + swz(n*32 + l31, ks*32 + hi*16));
        s = MFMA32(kf, aq[ks], s);
      }
      mk_pb(s, ps, pb[2*n], pb[2*n+1]);
    }
    #pragma unroll
    for (int m = 0; m < 2; ++m)
      #pragma unroll
      for (int ks = 0; ks < 4; ++ks) {
        bf16x8 vf = *(const bf16x8*)(lVc + swz(m*32 + l31, ks*32 + hi*16));
        acc[m] = MFMA32(vf, pb[ks], acc[m]);
      }
    __syncthreads();
    cur ^= 1;
  }
#undef STAGE

  // ---- in-block combine: half-1 -> LDS (pitch 68 f32, region 2208 f32 per q-wave) ----
  ps += __shfl_xor(ps, 32, 64);
  float* cb = (float*)smem;
  if (half == 1) {
    float* dst = cb + qw * 2208;
    #pragma unroll
    for (int m = 0; m < 2; ++m)
      #pragma unroll
      for (int rq = 0; rq < 4; ++rq) {
        f32x4 v = {acc[m][rq*4], acc[m][rq*4+1], acc[m][rq*4+2], acc[m][rq*4+3]};
        *(f32x4*)(dst + l31*68 + m*32 + rq*8 + hi*4) = v;
      }
    if (hi == 0) dst[2176 + l31] = ps;
  }
  __syncthreads();
  if (half == 0) {
    const float* src = cb + qw * 2208;
    float inv = 1.0f / (ps + src[2176 + l31]);
    u16* obase = ob + ((size_t)(b*2048 + q0 + l31))*512 + h*64;
    const u16* qrb = qb + ((size_t)(b*2048 + q0 + l31))*512 + h*64;
    #pragma unroll
    for (int m = 0; m < 2; ++m)
      #pragma unroll
      for (int rq = 0; rq < 4; ++rq) {
        f32x4 other = *(const f32x4*)(src + l31*68 + m*32 + rq*8 + hi*4);
        u16x4 qr4 = *(const u16x4*)(qrb + m*32 + rq*8 + hi*4);
        u16x4 o4;
        #pragma unroll
        for (int e = 0; e < 4; ++e)
          o4[e] = f2bf((acc[m][rq*4 + e] + other[e])*inv + bf2f(qr4[e])*UNSCALE);
        *(u16x4*)(obase + m*32 + rq*8 + hi*4) = o4;
      }
  }
}

// ---------------- fused tail: LN0 (on-the-fly) -> Wo GEMM + ReLU + residual -> LN1 ------
__global__ __launch_bounds__(512) void tail_k(
    const u16* __restrict__ ob, const u16* __restrict__ Bt,
    const float* __restrict__ bo,
    const float* __restrict__ g0, const float* __restrict__ b0,
    const float* __restrict__ g1, const float* __restrict__ b1,
    float* __restrict__ out)
{
  __shared__ __align__(16) u16 lA[2][32*64];     // 4KB each
  __shared__ __align__(16) u16 lB[2][512*64];    // 64KB each
  __shared__ float mu0[32], rs0[32], mu1[32], rs1[32];
  __shared__ float ps1[32][8], ss1[32][8];

  int row0 = blockIdx.x * 32;
  int t = threadIdx.x, lane = t & 63, wid = t >> 6;
  int l15 = lane & 15, lg = lane >> 4;

  // ---- LN0 stats: 16 threads per row, 32 elems each ----
  {
    int r = t >> 4, c0 = (t & 15) * 32;
    const u16* xp = ob + (size_t)(row0 + r)*512 + c0;
    float s = 0.0f, ss = 0.0f;
    #pragma unroll
    for (int j = 0; j < 4; ++j) {
      u16x8 v = *(const u16x8*)(xp + j*8);
      #pragma unroll
      for (int e = 0; e < 8; ++e) { float f = bf2f(v[e]); s += f; ss += f*f; }
    }
    #pragma unroll
    for (int m = 1; m < 16; m <<= 1) { s += __shfl_xor(s, m, 64); ss += __shfl_xor(ss, m, 64); }
    if ((t & 15) == 0) {
      float mu = s * (1.0f/512.0f);
      float var = ss * (1.0f/512.0f) - mu*mu;
      mu0[r] = mu; rs0[r] = rsqrtf(var + 1e-5f);
    }
  }
  __syncthreads();

  int ar = t >> 3, ak8 = t & 7;
  int br = t >> 3;
  int bsrc = ((t & 7) ^ (br & 7)) << 3;

  auto stageA = [&](int buf, int k0) {
    if (t < 256) {
      u16x8 x = *(const u16x8*)(ob + (size_t)(row0 + ar)*512 + k0 + ak8*8);
      f32x4 gv0 = *(const f32x4*)(g0 + k0 + ak8*8);
      f32x4 gv1 = *(const f32x4*)(g0 + k0 + ak8*8 + 4);
      f32x4 bv0 = *(const f32x4*)(b0 + k0 + ak8*8);
      f32x4 bv1 = *(const f32x4*)(b0 + k0 + ak8*8 + 4);
      float mu = mu0[ar], rs = rs0[ar];
      u16x8 h;
      #pragma unroll
      for (int j = 0; j < 4; ++j) {
        h[j]   = f2bf((bf2f(x[j])   - mu)*rs*gv0[j] + bv0[j]);
        h[j+4] = f2bf((bf2f(x[j+4]) - mu)*rs*gv1[j] + bv1[j]);
      }
      *(u16x8*)((char*)lA[buf] + swz(ar, ak8*16)) = h;
    }
  };

  #pragma unroll
  for (int i = 0; i < 8; ++i)
    gload16(Bt + (size_t)(br + i*64)*512 + bsrc, (char*)lB[0] + i*8192 + t*16);
  stageA(0, 0);
  __syncthreads();

  f32x4 acc[2][4] = {};
  int cur = 0;
  for (int k0 = 0; k0 < 512; k0 += 64) {
    if (k0 + 64 < 512) {
      #pragma unroll
      for (int i = 0; i < 8; ++i)
        gload16(Bt + (size_t)(br + i*64)*512 + k0 + 64 + bsrc, (char*)lB[cur^1] + i*8192 + t*16);
      stageA(cur^1, k0 + 64);
    }
    const char* lAc = (const char*)lA[cur];
    const char* lBc = (const char*)lB[cur];
    #pragma unroll
    for (int ks = 0; ks < 2; ++ks) {
      bf16x8 af[2], bfv[4];
      #pragma unroll
      for (int m = 0; m < 2; ++m)
        af[m] = *(const bf16x8*)(lAc + swz(m*16 + l15, ks*64 + lg*16));
      #pragma unroll
      for (int n = 0; n < 4; ++n)
        bfv[n] = *(const bf16x8*)(lBc + swz(wid*64 + n*16 + l15, ks*64 + lg*16));
      #pragma unroll
      for (int m = 0; m < 2; ++m)
        #pragma unroll
        for (int n = 0; n < 4; ++n)
          acc[m][n] = MFMA(af[m], bfv[n], acc[m][n]);
    }
    __syncthreads();
    cur ^= 1;
  }

  // ---- epilogue: G = H + relu(acc + bo); LN1 partials in-register ----
  float Gv[2][4][4];
  float sp[2][4] = {}, ssp[2][4] = {};
  #pragma unroll
  for (int n = 0; n < 4; ++n) {
    int colg = wid*64 + n*16 + l15;
    float bov = bo[colg];
    float g0c = g0[colg], b0c = b0[colg];
    #pragma unroll
    for (int m = 0; m < 2; ++m) {
      #pragma unroll
      for (int rr = 0; rr < 4; ++rr) {
        int rit = m*16 + lg*4 + rr;
        float H = (bf2f(ob[(size_t)(row0 + rit)*512 + colg]) - mu0[rit])*rs0[rit]*g0c + b0c;
        float G = H + fmaxf(acc[m][n][rr] + bov, 0.0f);
        Gv[m][n][rr] = G;
        sp[m][rr] += G;
        ssp[m][rr] += G*G;
      }
    }
  }
  #pragma unroll
  for (int msk = 1; msk < 16; msk <<= 1)
    #pragma unroll
    for (int m = 0; m < 2; ++m)
      #pragma unroll
      for (int rr = 0; rr < 4; ++rr) {
        sp[m][rr]  += __shfl_xor(sp[m][rr],  msk, 64);
        ssp[m][rr] += __shfl_xor(ssp[m][rr], msk, 64);
      }
  if (l15 == 0) {
    #pragma unroll
    for (int m = 0; m < 2; ++m)
      #pragma unroll
      for (int rr = 0; rr < 4; ++rr) {
        int rit = m*16 + lg*4 + rr;
        ps1[rit][wid] = sp[m][rr];
        ss1[rit][wid] = ssp[m][rr];
      }
  }
  __syncthreads();
  if (t < 32) {
    float s = 0.0f, ss = 0.0f;
    #pragma unroll
    for (int w = 0; w < 8; ++w) { s += ps1[t][w]; ss += ss1[t][w]; }
    float mu = s * (1.0f/512.0f);
    float var = ss * (1.0f/512.0f) - mu*mu;
    mu1[t] = mu; rs1[t] = rsqrtf(var + 1e-5f);
  }
  __syncthreads();
  #pragma unroll
  for (int n = 0; n < 4; ++n) {
    int colg = wid*64 + n*16 + l15;
    float g1c = g1[colg], b1c = b1[colg];
    #pragma unroll
    for (int m = 0; m < 2; ++m)
      #pragma unroll
      for (int rr = 0; rr < 4; ++rr) {
        int rit = m*16 + lg*4 + rr;
        out[(size_t)(row0 + rit)*512 + colg] =
            (Gv[m][n][rr] - mu1[rit])*rs1[rit]*g1c + b1c;
      }
  }
}

extern "C" void kernel_launch(void* const* d_in, const int* in_sizes, int n_in,
                              void* d_out, int out_size, void* d_ws, size_t ws_size,
                              hipStream_t stream)
{
  const float* Q   = (const float*)d_in[0];
  const float* K   = (const float*)d_in[1];
  const float* Wq  = (const float*)d_in[2];
  const float* bq  = (const float*)d_in[3];
  const float* Wk  = (const float*)d_in[4];
  const float* bk  = (const float*)d_in[5];
  const float* Wv  = (const float*)d_in[6];
  const float* bv  = (const float*)d_in[7];
  const float* Wo  = (const float*)d_in[8];
  const float* bo  = (const float*)d_in[9];
  const float* g0  = (const float*)d_in[10];
  const float* b0  = (const float*)d_in[11];
  const float* g1  = (const float*)d_in[12];
  const float* b1  = (const float*)d_in[13];

  char* ws = (char*)d_ws;
  // layout (MB): wt 0-2 | qbuf 2-10 | kbuf 10-18 | vt 18-26 | ob 26-34
  u16*   wt    = (u16*)(ws + 0);
  u16*   qbuf  = (u16*)(ws + (2u<<20));
  u16*   kbuf  = (u16*)(ws + (10u<<20));
  u16*   vt    = (u16*)(ws + (18u<<20));
  u16*   ob    = (u16*)(ws + (26u<<20));

  // 1. weight transpose+convert (Wq/bq scaled by 1/sqrt(512)*log2e)
  wprep_k<<<dim3(8, 8, 4), 256, 0, stream>>>(Wq, Wk, Wv, Wo, wt);
  // 2. projections: fused K+V (K staged once), V pre-transposed; XCD-grouped grid
  proj2_k<<<1024, 512, 0, stream>>>(Q, K, wt, bq, bk, bv, qbuf, kbuf, vt);
  // 3. attention, in-block KV-split + combine, XCD-swizzled grid -> ob (bf16, final)
  attn_k<<<512, 512, 0, stream>>>(qbuf, kbuf, vt, ob);
  // 4. fused tail: LN0 -> Wo GEMM + ReLU + residual -> LN1 -> out (fp32)
  tail_k<<<256, 512, 0, stream>>>(ob, wt + 3*262144, bo, g0, b0, g1, b1, (float*)d_out);
}